// Round 1
// baseline (1744.650 us; speedup 1.0000x reference)
//
#include <hip/hip_runtime.h>
#include <hip/hip_fp16.h>
#include <hip/hip_bf16.h>

// Packed bidirectional 2-layer LSTM for MI355X.
// Phases: setup (offsets/lengths) -> convert (bf16 casts, bias sum)
//   -> per layer: GEMM gates = x@Wih^T + b (bf16 MFMA) -> per-(seq,dir) recurrence.
// Workspace use ~153 MB.

#define CELL 128
#define GATES 512
#define DIN 256
#define NB 64

typedef float f4_t __attribute__((ext_vector_type(4)));
typedef short bf8_t __attribute__((ext_vector_type(8)));
typedef _Float16 h2_t __attribute__((ext_vector_type(2)));

static __device__ __forceinline__ unsigned short f32_bf16(float f) {
  union { float f; unsigned int u; } v; v.f = f;
  unsigned int u = v.u;
  return (unsigned short)((u + 0x7fffu + ((u >> 16) & 1u)) >> 16);
}

// ---------------- setup: exclusive cumsum + per-seq lengths ----------------
__global__ void k_setup(const int* __restrict__ bs, int T,
                        int* __restrict__ offsets, int* __restrict__ lengths) {
  __shared__ int sbs[1024];
  int t = threadIdx.x;
  sbs[t] = (t < T) ? bs[t] : 0;
  __syncthreads();
  int sum = 0;
  for (int i = 0; i < t; ++i) sum += sbs[i];
  if (t < T) offsets[t] = sum;
  if (t < NB) {
    int c = 0;
    for (int i = 0; i < T; ++i) c += (sbs[i] > t) ? 1 : 0;
    lengths[t] = c;
  }
}

// ---------------- convert: x->bf16, W_ih->bf16, bias sum ----------------
__global__ void k_convert(const float* __restrict__ x, unsigned short* __restrict__ xb, int nx,
                          const float* __restrict__ wih, unsigned short* __restrict__ wb, int nw,
                          const float* __restrict__ bih, const float* __restrict__ bhh,
                          float* __restrict__ bsum, int nb2) {
  int stride = gridDim.x * blockDim.x;
  int i0 = blockIdx.x * blockDim.x + threadIdx.x;
  for (int i = i0; i < nx; i += stride) xb[i] = f32_bf16(x[i]);
  for (int i = i0; i < nw; i += stride) wb[i] = f32_bf16(wih[i]);
  for (int i = i0; i < nb2; i += stride) bsum[i] = bih[i] + bhh[i];
}

// ---------------- GEMM: C(M,1024) f16 = A(M,256)bf16 @ W(rows lbase..+1023)^T + bias ----
__global__ __launch_bounds__(256) void k_gemm(
    const unsigned short* __restrict__ A,
    const unsigned short* __restrict__ W,   // (2048,256) bf16
    const float* __restrict__ bsum,         // (2048,)
    __half* __restrict__ C,
    int M, int lbase) {
  __shared__ __align__(16) unsigned short As[128 * 64];
  __shared__ __align__(16) unsigned short Bs[128 * 64];
  const int tid = threadIdx.x;
  const int lane = tid & 63;
  const int wave = tid >> 6;
  const int wm = wave >> 1, wn = wave & 1;   // 2x2 wave grid, 64x64 per wave
  const int m0 = blockIdx.x * 128;
  const int n0 = blockIdx.y * 128;

  f4_t acc[4][4];
#pragma unroll
  for (int i = 0; i < 4; ++i)
#pragma unroll
    for (int j = 0; j < 4; ++j) acc[i][j] = (f4_t){0.f, 0.f, 0.f, 0.f};

  for (int kt = 0; kt < 256; kt += 64) {
    // stage A,B tiles: linear LDS dest, inverse-XOR-swizzled global source (rule #21)
#pragma unroll
    for (int it = 0; it < 4; ++it) {
      int idx = it * 256 + tid;        // 16B units
      int row = idx >> 3;
      int gslot = (idx & 7) ^ (row & 7);
      int grow = m0 + row; if (grow > M - 1) grow = M - 1;
      __builtin_amdgcn_global_load_lds(
          (const __attribute__((address_space(1))) unsigned int*)(A + (size_t)grow * 256 + kt + gslot * 8),
          (__attribute__((address_space(3))) unsigned int*)(As + idx * 8), 16, 0, 0);
    }
#pragma unroll
    for (int it = 0; it < 4; ++it) {
      int idx = it * 256 + tid;
      int row = idx >> 3;
      int gslot = (idx & 7) ^ (row & 7);
      __builtin_amdgcn_global_load_lds(
          (const __attribute__((address_space(1))) unsigned int*)(W + (size_t)(lbase + n0 + row) * 256 + kt + gslot * 8),
          (__attribute__((address_space(3))) unsigned int*)(Bs + idx * 8), 16, 0, 0);
    }
    asm volatile("s_waitcnt vmcnt(0)" ::: "memory");
    __syncthreads();
#pragma unroll
    for (int kk = 0; kk < 2; ++kk) {
      bf8_t af[4], bfv[4];
#pragma unroll
      for (int i = 0; i < 4; ++i) {
        int arow = wm * 64 + i * 16 + (lane & 15);
        int aslot = (kk * 4 + (lane >> 4)) ^ (arow & 7);
        af[i] = *(const bf8_t*)(As + arow * 64 + aslot * 8);
        int brow = wn * 64 + i * 16 + (lane & 15);
        int bslot = (kk * 4 + (lane >> 4)) ^ (brow & 7);
        bfv[i] = *(const bf8_t*)(Bs + brow * 64 + bslot * 8);
      }
#pragma unroll
      for (int i = 0; i < 4; ++i)
#pragma unroll
        for (int j = 0; j < 4; ++j)
          acc[i][j] = __builtin_amdgcn_mfma_f32_16x16x32_bf16(af[i], bfv[j], acc[i][j], 0, 0, 0);
    }
    __syncthreads();
  }
  // epilogue: C[row][col], row=(lane>>4)*4+r, col=lane&15 (m89 mapping)
#pragma unroll
  for (int i = 0; i < 4; ++i) {
#pragma unroll
    for (int j = 0; j < 4; ++j) {
      int col = n0 + wn * 64 + j * 16 + (lane & 15);
      float bv = bsum[lbase + col];
#pragma unroll
      for (int r = 0; r < 4; ++r) {
        int row = m0 + wm * 64 + i * 16 + (lane >> 4) * 4 + r;
        if (row < M) C[(size_t)row * 1024 + col] = (__half)(acc[i][j][r] + bv);
      }
    }
  }
}

// ---------------- recurrence: one workgroup per (seq, dir) chain ----------------
#if defined(__has_builtin)
#if __has_builtin(__builtin_amdgcn_fdot2)
#define HAVE_FDOT2 1
#endif
#endif

static __device__ __forceinline__ float fdot2(h2_t a, h2_t b, float c) {
#ifdef HAVE_FDOT2
  return __builtin_amdgcn_fdot2(a, b, c, false);
#else
  return c + (float)a[0] * (float)b[0] + (float)a[1] * (float)b[1];
#endif
}
static __device__ __forceinline__ float sigm(float x) { return 1.f / (1.f + __expf(-x)); }
static __device__ __forceinline__ float tanh_(float x) { return 1.f - 2.f / (1.f + __expf(2.f * x)); }

template <int LAYER>
__global__ __launch_bounds__(512) void k_rec(
    const __half* __restrict__ gates,     // (TOTAL,1024): [tok][d*512+g]
    const int* __restrict__ offsets,      // (T,)
    const int* __restrict__ lengths,      // (NB,)
    const float* __restrict__ h0,         // (4,NB,CELL)
    const float* __restrict__ c0,
    const float* __restrict__ Whh,        // (4,512,128) f32
    unsigned short* __restrict__ y1,      // (TOTAL,256) bf16 (LAYER==0)
    float* __restrict__ outp,             // (TOTAL,256) f32  (LAYER==1)
    float* __restrict__ hn, float* __restrict__ cn,
    int T) {
  const int b = blockIdx.x >> 1;
  const int d = blockIdx.x & 1;
  const int k = 2 * LAYER + d;
  const int tid = threadIdx.x;
  const int q = tid & 127;        // cell index
  const int s = tid >> 7;         // k-slice (32 wide), uniform per wave pair
  const int L = lengths[b];

  __shared__ __align__(16) __half hbuf[CELL];
  __shared__ float4 part[512];
  __shared__ int toks[1024];

  for (int t = tid; t < T; t += 512) toks[t] = offsets[t] + b;

  // Per-thread weights: gate rows {q, 128+q, 256+q, 384+q}, k in [32s,32s+32), f16 pairs.
  h2_t wp[4][16];
  {
    const float* Wb = Whh + (size_t)k * GATES * CELL;
#pragma unroll
    for (int gi = 0; gi < 4; ++gi) {
      const float* rowp = Wb + (size_t)(gi * CELL + q) * CELL + s * 32;
#pragma unroll
      for (int j = 0; j < 16; ++j) {
        h2_t p; p[0] = (_Float16)rowp[2 * j]; p[1] = (_Float16)rowp[2 * j + 1];
        wp[gi][j] = p;
      }
    }
  }

  float hcur = 0.f, ccur = 0.f;
  if (tid < CELL) {
    hcur = h0[(size_t)k * NB * CELL + b * CELL + q];
    ccur = c0[(size_t)k * NB * CELL + b * CELL + q];
    hbuf[q] = (__half)hcur;
  }
  __syncthreads();   // toks + initial hbuf visible

  __half gx0 = __half(0.f), gx1 = __half(0.f), gx2 = __half(0.f), gx3 = __half(0.f);
  int tokc = 0;
  if (tid < CELL && L > 0) {
    tokc = toks[d ? (L - 1) : 0];
    const __half* gp = gates + (size_t)tokc * 1024 + d * GATES + q;
    gx0 = gp[0]; gx1 = gp[CELL]; gx2 = gp[2 * CELL]; gx3 = gp[3 * CELL];
  }

  for (int n = 0; n < L; ++n) {
    // dot stage (all 512 threads): 4 gates x 32 k as 16 dot2 each
    const h2_t* hsh = (const h2_t*)hbuf;
    h2_t hp[16];
#pragma unroll
    for (int j = 0; j < 16; ++j) hp[j] = hsh[s * 16 + j];
    float a0 = 0.f, a1 = 0.f, a2 = 0.f, a3 = 0.f;
#pragma unroll
    for (int j = 0; j < 16; ++j) {
      a0 = fdot2(wp[0][j], hp[j], a0);
      a1 = fdot2(wp[1][j], hp[j], a1);
      a2 = fdot2(wp[2][j], hp[j], a2);
      a3 = fdot2(wp[3][j], hp[j], a3);
    }
    part[tid] = make_float4(a0, a1, a2, a3);
    __syncthreads();   // barrier A: partials ready, hbuf reads done
    if (tid < CELL) {
      float4 v0 = part[q], v1 = part[q + 128], v2 = part[q + 256], v3 = part[q + 384];
      float gi = v0.x + v1.x + v2.x + v3.x + __half2float(gx0);
      float gf = v0.y + v1.y + v2.y + v3.y + __half2float(gx1);
      float gg = v0.z + v1.z + v2.z + v3.z + __half2float(gx2);
      float go = v0.w + v1.w + v2.w + v3.w + __half2float(gx3);
      // prefetch next step's gate-x (hides latency across barrier+dot stage)
      int tokn = tokc;
      if (n + 1 < L) {
        tokn = toks[d ? (L - 2 - n) : (n + 1)];
        const __half* gp = gates + (size_t)tokn * 1024 + d * GATES + q;
        gx0 = gp[0]; gx1 = gp[CELL]; gx2 = gp[2 * CELL]; gx3 = gp[3 * CELL];
      }
      float fi = sigm(gi), ff = sigm(gf), fg = tanh_(gg), fo = sigm(go);
      ccur = ff * ccur + fi * fg;
      hcur = fo * tanh_(ccur);
      hbuf[q] = (__half)hcur;
      if (LAYER == 0)
        y1[(size_t)tokc * 256 + d * CELL + q] = f32_bf16(hcur);
      else
        outp[(size_t)tokc * 256 + d * CELL + q] = hcur;
      tokc = tokn;
    }
    __syncthreads();   // barrier B: new h visible, part consumable
  }
  if (tid < CELL) {
    hn[(size_t)k * NB * CELL + b * CELL + q] = hcur;
    cn[(size_t)k * NB * CELL + b * CELL + q] = ccur;
  }
}

// ---------------- launch ----------------
extern "C" void kernel_launch(void* const* d_in, const int* in_sizes, int n_in,
                              void* d_out, int out_size, void* d_ws, size_t ws_size,
                              hipStream_t stream) {
  const float* x   = (const float*)d_in[0];
  const int*   bs  = (const int*)d_in[1];
  const float* h0  = (const float*)d_in[2];
  const float* c0  = (const float*)d_in[3];
  const float* wih = (const float*)d_in[4];
  const float* whh = (const float*)d_in[5];
  const float* bih = (const float*)d_in[6];
  const float* bhh = (const float*)d_in[7];
  const int TOTAL = in_sizes[0] / DIN;
  const int T = in_sizes[1];

  char* ws = (char*)d_ws;
  size_t off = 0;
  auto alloc = [&](size_t bytes) {
    void* p = ws + off;
    off = (off + bytes + 255) & ~(size_t)255;
    return p;
  };
  int* offsets        = (int*)alloc((size_t)T * 4);
  int* lengths        = (int*)alloc(NB * 4);
  float* bsum         = (float*)alloc(2048 * 4);
  unsigned short* wb  = (unsigned short*)alloc((size_t)2048 * 256 * 2);
  unsigned short* xb  = (unsigned short*)alloc((size_t)TOTAL * 256 * 2);
  unsigned short* y1  = (unsigned short*)alloc((size_t)TOTAL * 256 * 2);
  __half* gates       = (__half*)alloc((size_t)TOTAL * 1024 * 2);
  // total ~153 MB; assumed <= ws_size

  float* outp = (float*)d_out;
  float* hn = outp + (size_t)TOTAL * 256;
  float* cn = hn + 4 * NB * CELL;

  k_setup<<<1, 1024, 0, stream>>>(bs, T, offsets, lengths);
  k_convert<<<1024, 256, 0, stream>>>(x, xb, TOTAL * 256,
                                      wih, wb, 4 * GATES * DIN,
                                      bih, bhh, bsum, 2048);
  dim3 ggrid((TOTAL + 127) / 128, 8);
  // layer 0
  k_gemm<<<ggrid, 256, 0, stream>>>(xb, wb, bsum, gates, TOTAL, 0);
  k_rec<0><<<NB * 2, 512, 0, stream>>>(gates, offsets, lengths, h0, c0, whh,
                                       y1, nullptr, hn, cn, T);
  // layer 1
  k_gemm<<<ggrid, 256, 0, stream>>>(y1, wb, bsum, gates, TOTAL, 1024);
  k_rec<1><<<NB * 2, 512, 0, stream>>>(gates, offsets, lengths, h0, c0, whh,
                                       nullptr, outp, hn, cn, T);
}